// Round 11
// baseline (63.011 us; speedup 1.0000x reference)
//
#include <hip/hip_runtime.h>
#include <hip/hip_bf16.h>

#define NB 4
#define NN 512
#define ND 128
#define NH 4
#define NK 32

constexpr float EPSV = 1e-6f;
constexpr float CF   = 2.8853900817779268f;   // 2/ln2
constexpr float L2E  = 1.4426950408889634f;   // log2(e)
constexpr float LN2V = 0.6931471805599453f;   // ln(2)
constexpr float EXPCUT = 25.0f;               // skip terms < e^-25 (rigorous bound)

__device__ __forceinline__ float4 ld4(const float* __restrict__ p) {
  return *reinterpret_cast<const float4*>(p);
}

// Kernel 1: x2 + projections ai' = (x@W1a + b1)*CF, aj' = (x@W1b)*CF.
// aj goes to ajRow (row layout, fallback) OR ajT (j-contiguous, main path).
// Block 0 thread 0 computes the rigorous skip threshold dnth.
__global__ __launch_bounds__(256) void dgf_proj(
    const float* __restrict__ x, const float* __restrict__ W1,
    const float* __restrict__ b1, const float* __restrict__ W2,
    const float* __restrict__ b2, float* __restrict__ ai2,
    float* __restrict__ ajRow, float* __restrict__ ajT,
    float* __restrict__ x2n, float* __restrict__ dnthp) {
  __shared__ float xr[8][ND];
  const int t = threadIdx.x;
  const int blk = blockIdx.x;
  const int b = blk >> 6;
  const int n0 = (blk & 63) << 3;
  const float* xb = x + (size_t)(b * NN + n0) * ND;
  {
    const int row = t >> 5, c = t & 31;
    *reinterpret_cast<float4*>(&xr[row][c * 4]) = ld4(xb + row * ND + c * 4);
  }
  if (blk == 0 && t == 0) {
    // sigma <= softplus(max_h(b2 + sum_k |W2|)); terms with
    // dist > EXPCUT*(2*sigmax^2+eps) are <= e^-EXPCUT -> skippable.
    float m = -1e30f;
    for (int h = 0; h < NH; ++h) {
      float sa = b2[h];
      for (int k = 0; k < NK; ++k) sa += fabsf(W2[h * NK + k]);
      m = fmaxf(m, sa);
    }
    const float e2 = __builtin_amdgcn_exp2f(m * L2E);
    const float lp = __builtin_amdgcn_logf(e2 + 1.f) * LN2V;
    const float sm = (m > 15.f) ? m : lp;          // softplus(m)
    dnthp[0] = -L2E * EXPCUT * fmaf(2.f * sm, sm, EPSV);
  }
  __syncthreads();
  if (t < 8) {
    float s = 0.f;
    for (int d = 0; d < ND; ++d) s = fmaf(xr[t][d], xr[t][d], s);
    x2n[b * NN + n0 + t] = s;
  }
  const int h = t >> 6, part = (t >> 5) & 1, k = t & 31;
  const float* w1p = W1 + (size_t)(h * 256 + part * 128) * NK + k;
  float acc[8] = {0.f, 0.f, 0.f, 0.f, 0.f, 0.f, 0.f, 0.f};
  for (int d = 0; d < ND; d += 4) {
    const float w0 = w1p[(d + 0) * NK];
    const float w1v = w1p[(d + 1) * NK];
    const float w2v = w1p[(d + 2) * NK];
    const float w3v = w1p[(d + 3) * NK];
#pragma unroll
    for (int row = 0; row < 8; ++row) {
      const float4 xv = *reinterpret_cast<const float4*>(&xr[row][d]);
      float a = acc[row];
      a = fmaf(xv.x, w0, a);
      a = fmaf(xv.y, w1v, a);
      a = fmaf(xv.z, w2v, a);
      a = fmaf(xv.w, w3v, a);
      acc[row] = a;
    }
  }
  if (part == 0) {
    const float bb = b1[h * NK + k];
#pragma unroll
    for (int row = 0; row < 8; ++row) {
      ai2[((size_t)(b * NN + n0 + row) * NH + h) * NK + k] =
          (acc[row] + bb) * CF;
    }
  } else {
    if (ajT) {
#pragma unroll
      for (int row = 0; row < 8; ++row) {
        ajT[((size_t)(b * 128 + h * NK + k)) * NN + n0 + row] = acc[row] * CF;
      }
    } else {
#pragma unroll
      for (int row = 0; row < 8; ++row) {
        ajRow[((size_t)(b * NN + n0 + row) * NH + h) * NK + k] = acc[row] * CF;
      }
    }
  }
}

// Kernel 2: distn[b][i][j] = -L2E * max(x2i + x2j - 2*<xi,xj>, 0), plus
// per-(4i x 64j)-tile max-dn flags via wave reduction.
__global__ __launch_bounds__(256) void dgf_dist(
    const float* __restrict__ x, const float* __restrict__ x2n,
    float* __restrict__ distn, float* __restrict__ flags) {
  __shared__ float4 xi4s[8 * 32];   // 8 i-rows   4KB
  __shared__ float x2is[8];
  const int t = threadIdx.x;
  const int blk = blockIdx.x;
  const int b = blk >> 7;
  const int igrp = (blk >> 1) & 63;
  const int jh = blk & 1;
  const int i0 = igrp << 3;
  const int j = (jh << 8) + t;

  {
    const int row = t >> 5, c = t & 31;
    xi4s[t] = ld4(x + (size_t)(b * NN + i0 + row) * ND + c * 4);
  }
  if (t < 8) x2is[t] = x2n[b * NN + i0 + t];
  __syncthreads();

  float g[8] = {0.f, 0.f, 0.f, 0.f, 0.f, 0.f, 0.f, 0.f};
  const float* xj = x + (size_t)(b * NN + j) * ND;
  for (int c = 0; c < 32; ++c) {
    const float4 a = ld4(xj + c * 4);
#pragma unroll
    for (int r = 0; r < 8; ++r) {
      const float4 xv = xi4s[r * 32 + c];
      float u = g[r];
      u = fmaf(xv.x, a.x, u); u = fmaf(xv.y, a.y, u);
      u = fmaf(xv.z, a.z, u); u = fmaf(xv.w, a.w, u);
      g[r] = u;
    }
  }
  const float x2j = x2n[b * NN + j];
  float dn[8];
  float* dp = distn + (size_t)b * NN * NN + (size_t)i0 * NN + j;
#pragma unroll
  for (int r = 0; r < 8; ++r) {
    dn[r] = -L2E * fmaxf(x2is[r] + x2j - 2.f * g[r], 0.f);
    dp[(size_t)r * NN] = dn[r];
  }
  // tile flags: tiles are (4 i-rows x 64 j); this wave covers 64 j exactly.
  float m03 = fmaxf(fmaxf(dn[0], dn[1]), fmaxf(dn[2], dn[3]));
  float m47 = fmaxf(fmaxf(dn[4], dn[5]), fmaxf(dn[6], dn[7]));
#pragma unroll
  for (int off = 32; off >= 1; off >>= 1) {
    m03 = fmaxf(m03, __shfl_xor(m03, off));
    m47 = fmaxf(m47, __shfl_xor(m47, off));
  }
  if ((t & 63) == 0) {
    const int jt = (jh << 2) + (t >> 6);
    const int it = i0 >> 2;
    flags[((size_t)b * 128 + it) * 8 + jt]     = m03;
    flags[((size_t)b * 128 + it + 1) * 8 + jt] = m47;
  }
}

// Kernel 3: band adj. One 64-thread block per (4i x 64j) tile; cold tiles
// exit immediately (no barrier coupling). Hot tiles: full B2, adj written
// IN PLACE over the dist buffer (block owns its tile).
__global__ __launch_bounds__(64, 4) void dgf_band(
    const float* __restrict__ W2, const float* __restrict__ b2,
    const float* __restrict__ ai2, const float* __restrict__ ajT,
    const float* __restrict__ dnthp, const float* __restrict__ flags,
    float* __restrict__ buf) {
  __shared__ float4 ai2s4[4 * 32];   // 4 i-rows of ai'  2KB
  __shared__ float4 w2s4[32];        // -2*W2
  __shared__ float b2s[4];           // b2[h] + sum_k W2[h][k]
  const int t = threadIdx.x;
  const int blk = blockIdx.x;
  const int jt = blk & 7;
  const int it = (blk >> 3) & 127;
  const int b  = blk >> 10;

  const float dnth = dnthp[0];
  const float flag = flags[((size_t)b * 128 + it) * 8 + jt];
  if (!(flag > dnth)) return;     // cold tile: adj ~ 0 (<= e^-EXPCUT), skip

  const int i0 = it << 2;
  const int j  = (jt << 6) + t;

  {
    const int r = t >> 5, c = t & 31;
    ai2s4[t]      = ld4(ai2 + (size_t)(b * NN + i0 + r) * (NH * NK) + c * 4);
    ai2s4[t + 64] = ld4(ai2 + (size_t)(b * NN + i0 + 2 + r) * (NH * NK) + c * 4);
  }
  if (t < 32) {
    const float4 w = ld4(W2 + t * 4);
    float4 wn;
    wn.x = -2.f * w.x; wn.y = -2.f * w.y; wn.z = -2.f * w.z; wn.w = -2.f * w.w;
    w2s4[t] = wn;
  } else if (t < 36) {
    const int h = t - 32;
    float sw = 0.f;
    for (int k = 0; k < NK; ++k) sw += W2[h * NK + k];
    b2s[h] = b2[h] + sw;
  }
  __syncthreads();

  float dn[4];
  float* bp_ = buf + ((size_t)(b * NN + i0)) * NN + j;
#pragma unroll
  for (int r = 0; r < 4; ++r) dn[r] = bp_[(size_t)r * NN];

  float adjv[4] = {0.f, 0.f, 0.f, 0.f};
  const float* ajTb = ajT + (size_t)b * 128 * NN + j;
  for (int h = 0; h < NH; ++h) {
    float s[4] = {0.f, 0.f, 0.f, 0.f};
#pragma unroll
    for (int kc = 0; kc < 8; ++kc) {
      const float4 w2c = w2s4[h * 8 + kc];   // already -2*W2
      const int hk = h * NK + kc * 4;
      const float a0 = ajTb[(size_t)(hk + 0) * NN];
      const float a1 = ajTb[(size_t)(hk + 1) * NN];
      const float a2 = ajTb[(size_t)(hk + 2) * NN];
      const float a3 = ajTb[(size_t)(hk + 3) * NN];
#pragma unroll
      for (int r = 0; r < 4; ++r) {
        const float4 ac = ai2s4[r * 32 + h * 8 + kc];
        float z, rc, sr = s[r];
        z = ac.x + a0;
        rc = __builtin_amdgcn_rcpf(__builtin_amdgcn_exp2f(z) + 1.f);
        sr = fmaf(w2c.x, rc, sr);
        z = ac.y + a1;
        rc = __builtin_amdgcn_rcpf(__builtin_amdgcn_exp2f(z) + 1.f);
        sr = fmaf(w2c.y, rc, sr);
        z = ac.z + a2;
        rc = __builtin_amdgcn_rcpf(__builtin_amdgcn_exp2f(z) + 1.f);
        sr = fmaf(w2c.z, rc, sr);
        z = ac.w + a3;
        rc = __builtin_amdgcn_rcpf(__builtin_amdgcn_exp2f(z) + 1.f);
        sr = fmaf(w2c.w, rc, sr);
        s[r] = sr;
      }
    }
#pragma unroll
    for (int r = 0; r < 4; ++r) {
      const float si = s[r] + b2s[h];       // + (b2 + sum_k W2)
      const float e2 = __builtin_amdgcn_exp2f(si * L2E);
      const float lp = __builtin_amdgcn_logf(e2 + 1.f) * LN2V;
      const float sp = (si > 15.f) ? si : lp;   // softplus
      const float den = fmaf(2.f * sp, sp, EPSV);
      const float rr = __builtin_amdgcn_rcpf(den);
      adjv[r] += __builtin_amdgcn_exp2f(dn[r] * rr);
    }
  }
#pragma unroll
  for (int r = 0; r < 4; ++r) bp_[(size_t)r * NN] = adjv[r] * 0.25f;
}

// Kernel 4: h_out = adj @ x ; out = h_out @ Wp + bp, with flag-based
// skipping of cold j-tiles (their adj is ~0 and was never written).
__global__ __launch_bounds__(512, 4) void dgf_hout(
    const float* __restrict__ x, const float* __restrict__ Wp,
    const float* __restrict__ bp, const float* __restrict__ buf,
    const float* __restrict__ flags, const float* __restrict__ dnthp,
    float* __restrict__ out) {
  __shared__ float4 adjs4[512];      // [j] -> (r0..r3)  8KB
  __shared__ float pcbuf[16 * 512];  // 32KB: C partials; reused as pd in D
  __shared__ float hsT[4 * 128];     // [r][e]  2KB
  __shared__ float flag_s[8];
  __shared__ float dnth_s;
  const int t = threadIdx.x;
  const int blk = blockIdx.x;
  const int b = blk >> 7;
  const int i0 = (blk & 127) << 2;
  const int it = i0 >> 2;

  if (t < 8) flag_s[t] = flags[((size_t)b * 128 + it) * 8 + t];
  if (t == 8) dnth_s = dnthp[0];

  // stage adj rows with transpose into [j][r]; cold tiles -> zeros
  {
    const int r = t >> 7, j0 = (t & 127) << 2;
    const int jt = j0 >> 6;
    const float dth = dnthp[0];
    const bool hot = flags[((size_t)b * 128 + it) * 8 + jt] > dth;
    float4 a = {0.f, 0.f, 0.f, 0.f};
    if (hot) a = ld4(buf + ((size_t)(b * NN + i0 + r)) * NN + j0);
    float* as = reinterpret_cast<float*>(adjs4);
    as[(j0 + 0) * 4 + r] = a.x;
    as[(j0 + 1) * 4 + r] = a.y;
    as[(j0 + 2) * 4 + r] = a.z;
    as[(j0 + 3) * 4 + r] = a.w;
  }
  __syncthreads();

  // Phase C: h_out = adj @ x, skipping cold j-tiles (wave-uniform branch:
  // a wave = 2 jp-groups = exactly one 64-j tile).
  {
    const int dg = t & 31, jp = t >> 5;   // 16 j-groups of 32 j's
    float4 f0 = {0,0,0,0}, f1 = {0,0,0,0}, f2 = {0,0,0,0}, f3 = {0,0,0,0};
    if (flag_s[jp >> 1] > dnth_s) {
      const float* xb = x + (size_t)(b * NN) * ND;
      for (int u = 0; u < 32; ++u) {
        const int j = jp * 32 + u;
        const float4 a = adjs4[j];
        const float4 xv = ld4(xb + (size_t)j * ND + dg * 4);
        f0.x = fmaf(a.x, xv.x, f0.x); f0.y = fmaf(a.x, xv.y, f0.y);
        f0.z = fmaf(a.x, xv.z, f0.z); f0.w = fmaf(a.x, xv.w, f0.w);
        f1.x = fmaf(a.y, xv.x, f1.x); f1.y = fmaf(a.y, xv.y, f1.y);
        f1.z = fmaf(a.y, xv.z, f1.z); f1.w = fmaf(a.y, xv.w, f1.w);
        f2.x = fmaf(a.z, xv.x, f2.x); f2.y = fmaf(a.z, xv.y, f2.y);
        f2.z = fmaf(a.z, xv.z, f2.z); f2.w = fmaf(a.z, xv.w, f2.w);
        f3.x = fmaf(a.w, xv.x, f3.x); f3.y = fmaf(a.w, xv.y, f3.y);
        f3.z = fmaf(a.w, xv.z, f3.z); f3.w = fmaf(a.w, xv.w, f3.w);
      }
    }
    float4* pc4 = reinterpret_cast<float4*>(pcbuf);
    pc4[jp * 128 + 0 * 32 + dg] = f0;
    pc4[jp * 128 + 1 * 32 + dg] = f1;
    pc4[jp * 128 + 2 * 32 + dg] = f2;
    pc4[jp * 128 + 3 * 32 + dg] = f3;
  }
  __syncthreads();
  {
    float v = 0.f;
#pragma unroll
    for (int jp = 0; jp < 16; ++jp) v += pcbuf[jp * 512 + t];
    hsT[t] = v;   // t = r*128 + e
  }
  __syncthreads();

  // Phase D: out = h_out @ Wp + bp
  {
    const int d = t & 127, eh = t >> 7;
    float a0 = 0.f, a1 = 0.f, a2 = 0.f, a3 = 0.f;
    for (int ee = 0; ee < 32; ++ee) {
      const int e = eh * 32 + ee;
      const float w = Wp[(size_t)e * ND + d];
      a0 = fmaf(hsT[0 * 128 + e], w, a0);
      a1 = fmaf(hsT[1 * 128 + e], w, a1);
      a2 = fmaf(hsT[2 * 128 + e], w, a2);
      a3 = fmaf(hsT[3 * 128 + e], w, a3);
    }
    float* pd = pcbuf;
    pd[eh * 512 + 0 * 128 + d] = a0;
    pd[eh * 512 + 1 * 128 + d] = a1;
    pd[eh * 512 + 2 * 128 + d] = a2;
    pd[eh * 512 + 3 * 128 + d] = a3;
  }
  __syncthreads();
  {
    const int r = t >> 7, d = t & 127;
    const float v = pcbuf[0 * 512 + t] + pcbuf[1 * 512 + t] +
                    pcbuf[2 * 512 + t] + pcbuf[3 * 512 + t] + bp[d];
    out[(size_t)(b * NN + i0 + r) * ND + d] = v;
  }
}

// Fallback: fused kernel (R3-verified, row layouts), used if ws is too small.
__global__ __launch_bounds__(512, 4) void dgf_fused(
    const float* __restrict__ x, const float* __restrict__ W2,
    const float* __restrict__ b2, const float* __restrict__ Wp,
    const float* __restrict__ bp, const float* __restrict__ ai2,
    const float* __restrict__ aj2, const float* __restrict__ x2n,
    float* __restrict__ out) {
  __shared__ float4 xi4[4 * 32];
  __shared__ float4 ai2s4[4 * 32];
  __shared__ float4 w2s4[32];
  __shared__ float x2is[4];
  __shared__ float b2s[4];
  __shared__ float4 adjs4[512];
  __shared__ float pcbuf[16 * 512];
  __shared__ float hsT[4 * 128];
  const int t = threadIdx.x;
  const int blk = blockIdx.x;
  const int b = blk >> 7;
  const int i0 = (blk & 127) << 2;

  if (t < 128) {
    const int r = t >> 5;
    const int c = t & 31;
    xi4[t]   = ld4(x   + (size_t)(b * NN + i0 + r) * ND + c * 4);
    ai2s4[t] = ld4(ai2 + (size_t)(b * NN + i0 + r) * (NH * NK) + c * 4);
  } else if (t < 160) {
    const float4 w = ld4(W2 + (t - 128) * 4);
    float4 wn;
    wn.x = -2.f * w.x; wn.y = -2.f * w.y; wn.z = -2.f * w.z; wn.w = -2.f * w.w;
    w2s4[t - 128] = wn;
  } else if (t < 164) {
    x2is[t - 160] = x2n[b * NN + i0 + (t - 160)];
  } else if (t < 168) {
    const int h = t - 164;
    float sw = 0.f;
    for (int k = 0; k < NK; ++k) sw += W2[h * NK + k];
    b2s[h] = b2[h] + sw;
  }
  __syncthreads();

  float dn[4];
  {
    float g[4] = {0.f, 0.f, 0.f, 0.f};
    const float* xj = x + (size_t)(b * NN + t) * ND;
    for (int c = 0; c < 32; ++c) {
      const float4 a = ld4(xj + c * 4);
#pragma unroll
      for (int r = 0; r < 4; ++r) {
        const float4 xv = xi4[r * 32 + c];
        float u = g[r];
        u = fmaf(xv.x, a.x, u); u = fmaf(xv.y, a.y, u);
        u = fmaf(xv.z, a.z, u); u = fmaf(xv.w, a.w, u);
        g[r] = u;
      }
    }
    const float x2j = x2n[b * NN + t];
#pragma unroll
    for (int r = 0; r < 4; ++r)
      dn[r] = -L2E * fmaxf(x2is[r] + x2j - 2.f * g[r], 0.f);
  }

  float adjv[4] = {0.f, 0.f, 0.f, 0.f};
  {
    const float* ajp = aj2 + (size_t)(b * NN + t) * (NH * NK);
    for (int h = 0; h < NH; ++h) {
      float4 aj[8];
#pragma unroll
      for (int c = 0; c < 8; ++c) aj[c] = ld4(ajp + h * NK + c * 4);
      float s[4] = {0.f, 0.f, 0.f, 0.f};
#pragma unroll
      for (int kc = 0; kc < 8; ++kc) {
        const float4 w2c = w2s4[h * 8 + kc];
        const float4 ajc = aj[kc];
#pragma unroll
        for (int r = 0; r < 4; ++r) {
          const float4 ac = ai2s4[r * 32 + h * 8 + kc];
          float z, rc, sr = s[r];
          z = ac.x + ajc.x;
          rc = __builtin_amdgcn_rcpf(__builtin_amdgcn_exp2f(z) + 1.f);
          sr = fmaf(w2c.x, rc, sr);
          z = ac.y + ajc.y;
          rc = __builtin_amdgcn_rcpf(__builtin_amdgcn_exp2f(z) + 1.f);
          sr = fmaf(w2c.y, rc, sr);
          z = ac.z + ajc.z;
          rc = __builtin_amdgcn_rcpf(__builtin_amdgcn_exp2f(z) + 1.f);
          sr = fmaf(w2c.z, rc, sr);
          z = ac.w + ajc.w;
          rc = __builtin_amdgcn_rcpf(__builtin_amdgcn_exp2f(z) + 1.f);
          sr = fmaf(w2c.w, rc, sr);
          s[r] = sr;
        }
      }
#pragma unroll
      for (int r = 0; r < 4; ++r) {
        const float si = s[r] + b2s[h];
        const float e2 = __builtin_amdgcn_exp2f(si * L2E);
        const float lp = __builtin_amdgcn_logf(e2 + 1.f) * LN2V;
        const float sp = (si > 15.f) ? si : lp;
        const float den = fmaf(2.f * sp, sp, EPSV);
        const float rr = __builtin_amdgcn_rcpf(den);
        adjv[r] += __builtin_amdgcn_exp2f(dn[r] * rr);
      }
    }
  }
  {
    float4 v;
    v.x = adjv[0] * 0.25f; v.y = adjv[1] * 0.25f;
    v.z = adjv[2] * 0.25f; v.w = adjv[3] * 0.25f;
    adjs4[t] = v;
  }
  __syncthreads();

  {
    const int dg = t & 31, jp = t >> 5;
    float4 f0 = {0,0,0,0}, f1 = {0,0,0,0}, f2 = {0,0,0,0}, f3 = {0,0,0,0};
    const float* xb = x + (size_t)(b * NN) * ND;
    for (int u = 0; u < 32; ++u) {
      const int j = jp * 32 + u;
      const float4 a = adjs4[j];
      const float4 xv = ld4(xb + (size_t)j * ND + dg * 4);
      f0.x = fmaf(a.x, xv.x, f0.x); f0.y = fmaf(a.x, xv.y, f0.y);
      f0.z = fmaf(a.x, xv.z, f0.z); f0.w = fmaf(a.x, xv.w, f0.w);
      f1.x = fmaf(a.y, xv.x, f1.x); f1.y = fmaf(a.y, xv.y, f1.y);
      f1.z = fmaf(a.y, xv.z, f1.z); f1.w = fmaf(a.y, xv.w, f1.w);
      f2.x = fmaf(a.z, xv.x, f2.x); f2.y = fmaf(a.z, xv.y, f2.y);
      f2.z = fmaf(a.z, xv.z, f2.z); f2.w = fmaf(a.z, xv.w, f2.w);
      f3.x = fmaf(a.w, xv.x, f3.x); f3.y = fmaf(a.w, xv.y, f3.y);
      f3.z = fmaf(a.w, xv.z, f3.z); f3.w = fmaf(a.w, xv.w, f3.w);
    }
    float4* pc4 = reinterpret_cast<float4*>(pcbuf);
    pc4[jp * 128 + 0 * 32 + dg] = f0;
    pc4[jp * 128 + 1 * 32 + dg] = f1;
    pc4[jp * 128 + 2 * 32 + dg] = f2;
    pc4[jp * 128 + 3 * 32 + dg] = f3;
  }
  __syncthreads();
  {
    float v = 0.f;
#pragma unroll
    for (int jp = 0; jp < 16; ++jp) v += pcbuf[jp * 512 + t];
    hsT[t] = v;
  }
  __syncthreads();
  {
    const int d = t & 127, eh = t >> 7;
    float a0 = 0.f, a1 = 0.f, a2 = 0.f, a3 = 0.f;
    for (int ee = 0; ee < 32; ++ee) {
      const int e = eh * 32 + ee;
      const float w = Wp[(size_t)e * ND + d];
      a0 = fmaf(hsT[0 * 128 + e], w, a0);
      a1 = fmaf(hsT[1 * 128 + e], w, a1);
      a2 = fmaf(hsT[2 * 128 + e], w, a2);
      a3 = fmaf(hsT[3 * 128 + e], w, a3);
    }
    float* pd = pcbuf;
    pd[eh * 512 + 0 * 128 + d] = a0;
    pd[eh * 512 + 1 * 128 + d] = a1;
    pd[eh * 512 + 2 * 128 + d] = a2;
    pd[eh * 512 + 3 * 128 + d] = a3;
  }
  __syncthreads();
  {
    const int d = t & 127;
    const float v = pcbuf[0 * 512 + t] + pcbuf[1 * 512 + t] +
                    pcbuf[2 * 512 + t] + pcbuf[3 * 512 + t] + bp[d];
    const int r = t >> 7;
    out[(size_t)(b * NN + i0 + r) * ND + d] = v;
  }
}

extern "C" void kernel_launch(void* const* d_in, const int* in_sizes, int n_in,
                              void* d_out, int out_size, void* d_ws, size_t ws_size,
                              hipStream_t stream) {
  const float* x  = (const float*)d_in[0];
  const float* W1 = (const float*)d_in[1];
  const float* b1 = (const float*)d_in[2];
  const float* W2 = (const float*)d_in[3];
  const float* b2 = (const float*)d_in[4];
  const float* Wp = (const float*)d_in[5];
  const float* bp = (const float*)d_in[6];
  float* out = (float*)d_out;

  const size_t nProj = (size_t)NB * NN * NH * NK;   // 262144
  const size_t nX2   = (size_t)NB * NN;             // 2048
  const size_t nFlag = (size_t)NB * 128 * 8;        // 4096
  const size_t nDist = (size_t)NB * NN * NN;        // 1048576

  float* ai2 = (float*)d_ws;
  float* x2n = ai2 + nProj;
  float* dnt = x2n + nX2;           // 4 floats (1 used)
  float* flg = dnt + 4;
  float* ajX = flg + nFlag;         // aj row (small) OR ajT (big)
  float* buf = ajX + nProj;         // dist, overwritten in place by adj

  const bool big =
      ws_size >= (nProj + nX2 + 4 + nFlag + nProj + nDist) * sizeof(float);

  dgf_proj<<<NB * NN / 8, 256, 0, stream>>>(
      x, W1, b1, W2, b2, ai2, big ? nullptr : ajX, big ? ajX : nullptr,
      x2n, dnt);

  if (big) {
    dgf_dist<<<NB * (NN / 8) * 2, 256, 0, stream>>>(x, x2n, buf, flg);
    dgf_band<<<NB * 128 * 8, 64, 0, stream>>>(W2, b2, ai2, ajX, dnt, flg, buf);
    dgf_hout<<<NB * (NN / 4), 512, 0, stream>>>(x, Wp, bp, buf, flg, dnt, out);
  } else {
    dgf_fused<<<NB * (NN / 4), 512, 0, stream>>>(x, W2, b2, Wp, bp, ai2, ajX,
                                                 x2n, out);
  }
}

// Round 12
// 55.736 us; speedup vs baseline: 1.1305x; 1.1305x over previous
//
#include <hip/hip_runtime.h>
#include <hip/hip_bf16.h>

#define NB 4
#define NN 512
#define ND 128
#define NH 4
#define NK 32

constexpr float EPSV = 1e-6f;
constexpr float CF   = 2.8853900817779268f;   // 2/ln2
constexpr float L2E  = 1.4426950408889634f;   // log2(e)
constexpr float LN2V = 0.6931471805599453f;   // ln(2)
constexpr float EXPCUT = 25.0f;               // skip terms < e^-25 (rigorous bound)

__device__ __forceinline__ float4 ld4(const float* __restrict__ p) {
  return *reinterpret_cast<const float4*>(p);
}

// XCD-pinning swizzle: workgroup->XCD is round-robin on blockIdx%8 (heuristic,
// perf-only). We map xcd = b*2 + hi so each batch's whole pipeline (proj ->
// dist -> adj) runs on a fixed XCD pair whose 4MB L2 holds that batch's
// ~3MB working set (x, aj2, ai2, dist strips).

// Kernel 1: x2 + projections ai' = (x@W1a + b1)*CF, aj' = (x@W1b)*CF.
// grid=256: xcd=blk&7 -> b=xcd>>1, hi=xcd&1; ngrp = hi*32 + (blk>>3).
__global__ __launch_bounds__(256) void dgf_proj(
    const float* __restrict__ x, const float* __restrict__ W1,
    const float* __restrict__ b1, const float* __restrict__ W2,
    const float* __restrict__ b2, float* __restrict__ ai2,
    float* __restrict__ aj2, float* __restrict__ x2n,
    float* __restrict__ dnthp) {
  __shared__ float xr[8][ND];
  const int t = threadIdx.x;
  const int blk = blockIdx.x;
  const int xcd = blk & 7;
  const int b = xcd >> 1;
  const int n0 = (((xcd & 1) << 5) + (blk >> 3)) << 3;
  const float* xb = x + (size_t)(b * NN + n0) * ND;
  {
    const int row = t >> 5, c = t & 31;
    *reinterpret_cast<float4*>(&xr[row][c * 4]) = ld4(xb + row * ND + c * 4);
  }
  if (blk == 0 && t == 0) {
    // sigma <= softplus(max_h(b2 + sum_k |W2|)); terms with
    // dist > EXPCUT*(2*sigmax^2+eps) are <= e^-EXPCUT -> skippable.
    float m = -1e30f;
    for (int h = 0; h < NH; ++h) {
      float sa = b2[h];
      for (int k = 0; k < NK; ++k) sa += fabsf(W2[h * NK + k]);
      m = fmaxf(m, sa);
    }
    const float e2 = __builtin_amdgcn_exp2f(m * L2E);
    const float lp = __builtin_amdgcn_logf(e2 + 1.f) * LN2V;
    const float sm = (m > 15.f) ? m : lp;          // softplus(m)
    dnthp[0] = -L2E * EXPCUT * fmaf(2.f * sm, sm, EPSV);
  }
  __syncthreads();
  if (t < 8) {
    float s = 0.f;
    for (int d = 0; d < ND; ++d) s = fmaf(xr[t][d], xr[t][d], s);
    x2n[b * NN + n0 + t] = s;
  }
  const int h = t >> 6, part = (t >> 5) & 1, k = t & 31;
  const float* w1p = W1 + (size_t)(h * 256 + part * 128) * NK + k;
  float acc[8] = {0.f, 0.f, 0.f, 0.f, 0.f, 0.f, 0.f, 0.f};
  for (int d = 0; d < ND; d += 4) {
    const float w0 = w1p[(d + 0) * NK];
    const float w1v = w1p[(d + 1) * NK];
    const float w2v = w1p[(d + 2) * NK];
    const float w3v = w1p[(d + 3) * NK];
#pragma unroll
    for (int row = 0; row < 8; ++row) {
      const float4 xv = *reinterpret_cast<const float4*>(&xr[row][d]);
      float a = acc[row];
      a = fmaf(xv.x, w0, a);
      a = fmaf(xv.y, w1v, a);
      a = fmaf(xv.z, w2v, a);
      a = fmaf(xv.w, w3v, a);
      acc[row] = a;
    }
  }
  const float bb = (part == 0) ? b1[h * NK + k] : 0.f;
  float* outp = (part == 0) ? ai2 : aj2;
#pragma unroll
  for (int row = 0; row < 8; ++row) {
    outp[((size_t)(b * NN + n0 + row) * NH + h) * NK + k] = (acc[row] + bb) * CF;
  }
}

// Kernel 1b: distn[b][i][j] = -L2E * max(x2i + x2j - 2*<xi,xj>, 0)
// grid=512: xcd=blk&7 -> b=xcd>>1, hi=xcd&1; idx=blk>>3 in [0,64):
// igrp = hi*32 + (idx>>1), jh = idx&1.  (istrip=2*igrp matches adj's split.)
__global__ __launch_bounds__(256) void dgf_dist(
    const float* __restrict__ x, const float* __restrict__ x2n,
    float* __restrict__ distn) {
  __shared__ float4 xi4s[8 * 32];   // 8 i-rows   4KB
  __shared__ float x2is[8];
  const int t = threadIdx.x;
  const int blk = blockIdx.x;
  const int xcd = blk & 7;
  const int idx = blk >> 3;
  const int b = xcd >> 1;
  const int igrp = ((xcd & 1) << 5) + (idx >> 1);
  const int jh = idx & 1;
  const int i0 = igrp << 3;
  const int j = (jh << 8) + t;

  {
    const int row = t >> 5, c = t & 31;
    xi4s[t] = ld4(x + (size_t)(b * NN + i0 + row) * ND + c * 4);
  }
  if (t < 8) x2is[t] = x2n[b * NN + i0 + t];
  __syncthreads();

  float g[8] = {0.f, 0.f, 0.f, 0.f, 0.f, 0.f, 0.f, 0.f};
  const float* xj = x + (size_t)(b * NN + j) * ND;
  for (int c = 0; c < 32; ++c) {
    const float4 a = ld4(xj + c * 4);
#pragma unroll
    for (int r = 0; r < 8; ++r) {
      const float4 xv = xi4s[r * 32 + c];
      float u = g[r];
      u = fmaf(xv.x, a.x, u); u = fmaf(xv.y, a.y, u);
      u = fmaf(xv.z, a.z, u); u = fmaf(xv.w, a.w, u);
      g[r] = u;
    }
  }
  const float x2j = x2n[b * NN + j];
  float* dp = distn + (size_t)b * NN * NN + (size_t)i0 * NN + j;
#pragma unroll
  for (int r = 0; r < 8; ++r) {
    dp[(size_t)r * NN] = -L2E * fmaxf(x2is[r] + x2j - 2.f * g[r], 0.f);
  }
}

// Kernel 2: B2 (heads, wave-skip) + C (adj@x) + D (proj), dist precomputed.
// grid=512: xcd=blk&7 -> b=xcd>>1, hi=xcd&1; istrip = hi*64 + (blk>>3).
__global__ __launch_bounds__(512, 4) void dgf_adj(
    const float* __restrict__ x, const float* __restrict__ W2,
    const float* __restrict__ b2, const float* __restrict__ Wp,
    const float* __restrict__ bp, const float* __restrict__ ai2,
    const float* __restrict__ aj2, const float* __restrict__ distn,
    float* __restrict__ out) {
  __shared__ float4 ai2s4[4 * 32];   // 4 i-rows of ai'      2KB
  __shared__ float4 w2s4[32];        // -2*W2 [h][k]         0.5KB
  __shared__ float b2s[4];           // b2[h] + sum_k W2[h][k]
  __shared__ float dnths;            // skip threshold in dn units
  __shared__ float4 adjs4[512];      // [j] -> (r0..r3)      8KB
  __shared__ float pcbuf[16 * 512];  // 32KB: C partials; reused as pd in D
  __shared__ float hsT[4 * 128];     // [r][e]  2KB
  const int t = threadIdx.x;
  const int blk = blockIdx.x;
  const int xcd = blk & 7;
  const int b = xcd >> 1;
  const int i0 = (((xcd & 1) << 6) + (blk >> 3)) << 2;

  // ---- Phase A ----
  if (t < 128) {
    const int r = t >> 5;
    const int c = t & 31;
    ai2s4[t] = ld4(ai2 + (size_t)(b * NN + i0 + r) * (NH * NK) + c * 4);
  } else if (t < 160) {
    const float4 w = ld4(W2 + (t - 128) * 4);
    float4 wn;
    wn.x = -2.f * w.x; wn.y = -2.f * w.y; wn.z = -2.f * w.z; wn.w = -2.f * w.w;
    w2s4[t - 128] = wn;
  } else if (t < 164) {
    const int h = t - 160;
    float sw = 0.f;
    for (int k = 0; k < NK; ++k) sw += W2[h * NK + k];
    b2s[h] = b2[h] + sw;
  } else if (t == 164) {
    float m = -1e30f;
    for (int h = 0; h < NH; ++h) {
      float sa = b2[h];
      for (int k = 0; k < NK; ++k) sa += fabsf(W2[h * NK + k]);
      m = fmaxf(m, sa);
    }
    const float e2 = __builtin_amdgcn_exp2f(m * L2E);
    const float lp = __builtin_amdgcn_logf(e2 + 1.f) * LN2V;
    const float sm = (m > 15.f) ? m : lp;          // softplus(m)
    dnths = -L2E * EXPCUT * fmaf(2.f * sm, sm, EPSV);
  }
  __syncthreads();

  // ---- distn loads ----
  float dn[4];
  {
    const float* dp = distn + (size_t)b * NN * NN + (size_t)i0 * NN + t;
#pragma unroll
    for (int r = 0; r < 4; ++r) dn[r] = dp[(size_t)r * NN];
  }

  // ---- Phase B2 (wave-skippable): sum_k w*tanh = sum_k w + sum_k (-2w)*sigmoid ----
  float adjv[4] = {0.f, 0.f, 0.f, 0.f};
  {
    const float dnth = dnths;
    const bool need = (dn[0] > dnth) || (dn[1] > dnth) ||
                      (dn[2] > dnth) || (dn[3] > dnth);
    if (__any(need)) {
      const float* ajp = aj2 + (size_t)(b * NN + t) * (NH * NK);
      for (int h = 0; h < NH; ++h) {
        float4 aj[8];
#pragma unroll
        for (int c = 0; c < 8; ++c) aj[c] = ld4(ajp + h * NK + c * 4);
        float s[4] = {0.f, 0.f, 0.f, 0.f};
#pragma unroll
        for (int kc = 0; kc < 8; ++kc) {
          const float4 w2c = w2s4[h * 8 + kc];   // already -2*W2
          const float4 ajc = aj[kc];
#pragma unroll
          for (int r = 0; r < 4; ++r) {
            const float4 ac = ai2s4[r * 32 + h * 8 + kc];
            float z, rc, sr = s[r];
            z = ac.x + ajc.x;
            rc = __builtin_amdgcn_rcpf(__builtin_amdgcn_exp2f(z) + 1.f);
            sr = fmaf(w2c.x, rc, sr);
            z = ac.y + ajc.y;
            rc = __builtin_amdgcn_rcpf(__builtin_amdgcn_exp2f(z) + 1.f);
            sr = fmaf(w2c.y, rc, sr);
            z = ac.z + ajc.z;
            rc = __builtin_amdgcn_rcpf(__builtin_amdgcn_exp2f(z) + 1.f);
            sr = fmaf(w2c.z, rc, sr);
            z = ac.w + ajc.w;
            rc = __builtin_amdgcn_rcpf(__builtin_amdgcn_exp2f(z) + 1.f);
            sr = fmaf(w2c.w, rc, sr);
            s[r] = sr;
          }
        }
#pragma unroll
        for (int r = 0; r < 4; ++r) {
          const float si = s[r] + b2s[h];       // + (b2 + sum_k W2)
          const float e2 = __builtin_amdgcn_exp2f(si * L2E);
          const float lp = __builtin_amdgcn_logf(e2 + 1.f) * LN2V;
          const float sp = (si > 15.f) ? si : lp;   // softplus
          const float den = fmaf(2.f * sp, sp, EPSV);
          const float rr = __builtin_amdgcn_rcpf(den);
          adjv[r] += __builtin_amdgcn_exp2f(dn[r] * rr);
        }
      }
    }
  }
  {
    float4 v;
    v.x = adjv[0] * 0.25f; v.y = adjv[1] * 0.25f;
    v.z = adjv[2] * 0.25f; v.w = adjv[3] * 0.25f;
    adjs4[t] = v;
  }
  __syncthreads();

  // ---- Phase C: h_out = adj @ x ----
  {
    const int dg = t & 31, jp = t >> 5;   // 16 j-groups of 32 j's
    float4 f0 = {0,0,0,0}, f1 = {0,0,0,0}, f2 = {0,0,0,0}, f3 = {0,0,0,0};
    const float* xb = x + (size_t)(b * NN) * ND;
    for (int u = 0; u < 32; ++u) {
      const int j = jp * 32 + u;
      const float4 a = adjs4[j];
      const float4 xv = ld4(xb + (size_t)j * ND + dg * 4);
      f0.x = fmaf(a.x, xv.x, f0.x); f0.y = fmaf(a.x, xv.y, f0.y);
      f0.z = fmaf(a.x, xv.z, f0.z); f0.w = fmaf(a.x, xv.w, f0.w);
      f1.x = fmaf(a.y, xv.x, f1.x); f1.y = fmaf(a.y, xv.y, f1.y);
      f1.z = fmaf(a.y, xv.z, f1.z); f1.w = fmaf(a.y, xv.w, f1.w);
      f2.x = fmaf(a.z, xv.x, f2.x); f2.y = fmaf(a.z, xv.y, f2.y);
      f2.z = fmaf(a.z, xv.z, f2.z); f2.w = fmaf(a.z, xv.w, f2.w);
      f3.x = fmaf(a.w, xv.x, f3.x); f3.y = fmaf(a.w, xv.y, f3.y);
      f3.z = fmaf(a.w, xv.z, f3.z); f3.w = fmaf(a.w, xv.w, f3.w);
    }
    float4* pc4 = reinterpret_cast<float4*>(pcbuf);
    pc4[jp * 128 + 0 * 32 + dg] = f0;
    pc4[jp * 128 + 1 * 32 + dg] = f1;
    pc4[jp * 128 + 2 * 32 + dg] = f2;
    pc4[jp * 128 + 3 * 32 + dg] = f3;
  }
  __syncthreads();
  {
    float v = 0.f;
#pragma unroll
    for (int jp = 0; jp < 16; ++jp) v += pcbuf[jp * 512 + t];
    hsT[t] = v;   // t = r*128 + e
  }
  __syncthreads();

  // ---- Phase D: out = h_out @ Wp + bp ----
  {
    const int d = t & 127, eh = t >> 7;
    float a0 = 0.f, a1 = 0.f, a2 = 0.f, a3 = 0.f;
    for (int ee = 0; ee < 32; ++ee) {
      const int e = eh * 32 + ee;
      const float w = Wp[(size_t)e * ND + d];
      a0 = fmaf(hsT[0 * 128 + e], w, a0);
      a1 = fmaf(hsT[1 * 128 + e], w, a1);
      a2 = fmaf(hsT[2 * 128 + e], w, a2);
      a3 = fmaf(hsT[3 * 128 + e], w, a3);
    }
    float* pd = pcbuf;
    pd[eh * 512 + 0 * 128 + d] = a0;
    pd[eh * 512 + 1 * 128 + d] = a1;
    pd[eh * 512 + 2 * 128 + d] = a2;
    pd[eh * 512 + 3 * 128 + d] = a3;
  }
  __syncthreads();
  {
    const int r = t >> 7, d = t & 127;
    const float v = pcbuf[0 * 512 + t] + pcbuf[1 * 512 + t] +
                    pcbuf[2 * 512 + t] + pcbuf[3 * 512 + t] + bp[d];
    out[(size_t)(b * NN + i0 + r) * ND + d] = v;
  }
}

// Fallback: fused kernel (R3-verified), used if ws is too small.
__global__ __launch_bounds__(512, 4) void dgf_fused(
    const float* __restrict__ x, const float* __restrict__ W2,
    const float* __restrict__ b2, const float* __restrict__ Wp,
    const float* __restrict__ bp, const float* __restrict__ ai2,
    const float* __restrict__ aj2, const float* __restrict__ x2n,
    float* __restrict__ out) {
  __shared__ float4 xi4[4 * 32];
  __shared__ float4 ai2s4[4 * 32];
  __shared__ float4 w2s4[32];
  __shared__ float x2is[4];
  __shared__ float b2s[4];
  __shared__ float4 adjs4[512];
  __shared__ float pcbuf[16 * 512];
  __shared__ float hsT[4 * 128];
  const int t = threadIdx.x;
  const int blk = blockIdx.x;
  const int b = blk >> 7;
  const int i0 = (blk & 127) << 2;

  if (t < 128) {
    const int r = t >> 5;
    const int c = t & 31;
    xi4[t]   = ld4(x   + (size_t)(b * NN + i0 + r) * ND + c * 4);
    ai2s4[t] = ld4(ai2 + (size_t)(b * NN + i0 + r) * (NH * NK) + c * 4);
  } else if (t < 160) {
    const float4 w = ld4(W2 + (t - 128) * 4);
    float4 wn;
    wn.x = -2.f * w.x; wn.y = -2.f * w.y; wn.z = -2.f * w.z; wn.w = -2.f * w.w;
    w2s4[t - 128] = wn;
  } else if (t < 164) {
    x2is[t - 160] = x2n[b * NN + i0 + (t - 160)];
  } else if (t < 168) {
    const int h = t - 164;
    float sw = 0.f;
    for (int k = 0; k < NK; ++k) sw += W2[h * NK + k];
    b2s[h] = b2[h] + sw;
  }
  __syncthreads();

  float dn[4];
  {
    float g[4] = {0.f, 0.f, 0.f, 0.f};
    const float* xj = x + (size_t)(b * NN + t) * ND;
    for (int c = 0; c < 32; ++c) {
      const float4 a = ld4(xj + c * 4);
#pragma unroll
      for (int r = 0; r < 4; ++r) {
        const float4 xv = xi4[r * 32 + c];
        float u = g[r];
        u = fmaf(xv.x, a.x, u); u = fmaf(xv.y, a.y, u);
        u = fmaf(xv.z, a.z, u); u = fmaf(xv.w, a.w, u);
        g[r] = u;
      }
    }
    const float x2j = x2n[b * NN + t];
#pragma unroll
    for (int r = 0; r < 4; ++r)
      dn[r] = -L2E * fmaxf(x2is[r] + x2j - 2.f * g[r], 0.f);
  }

  float adjv[4] = {0.f, 0.f, 0.f, 0.f};
  {
    const float* ajp = aj2 + (size_t)(b * NN + t) * (NH * NK);
    for (int h = 0; h < NH; ++h) {
      float4 aj[8];
#pragma unroll
      for (int c = 0; c < 8; ++c) aj[c] = ld4(ajp + h * NK + c * 4);
      float s[4] = {0.f, 0.f, 0.f, 0.f};
#pragma unroll
      for (int kc = 0; kc < 8; ++kc) {
        const float4 w2c = w2s4[h * 8 + kc];
        const float4 ajc = aj[kc];
#pragma unroll
        for (int r = 0; r < 4; ++r) {
          const float4 ac = ai2s4[r * 32 + h * 8 + kc];
          float z, rc, sr = s[r];
          z = ac.x + ajc.x;
          rc = __builtin_amdgcn_rcpf(__builtin_amdgcn_exp2f(z) + 1.f);
          sr = fmaf(w2c.x, rc, sr);
          z = ac.y + ajc.y;
          rc = __builtin_amdgcn_rcpf(__builtin_amdgcn_exp2f(z) + 1.f);
          sr = fmaf(w2c.y, rc, sr);
          z = ac.z + ajc.z;
          rc = __builtin_amdgcn_rcpf(__builtin_amdgcn_exp2f(z) + 1.f);
          sr = fmaf(w2c.z, rc, sr);
          z = ac.w + ajc.w;
          rc = __builtin_amdgcn_rcpf(__builtin_amdgcn_exp2f(z) + 1.f);
          sr = fmaf(w2c.w, rc, sr);
          s[r] = sr;
        }
      }
#pragma unroll
      for (int r = 0; r < 4; ++r) {
        const float si = s[r] + b2s[h];
        const float e2 = __builtin_amdgcn_exp2f(si * L2E);
        const float lp = __builtin_amdgcn_logf(e2 + 1.f) * LN2V;
        const float sp = (si > 15.f) ? si : lp;
        const float den = fmaf(2.f * sp, sp, EPSV);
        const float rr = __builtin_amdgcn_rcpf(den);
        adjv[r] += __builtin_amdgcn_exp2f(dn[r] * rr);
      }
    }
  }
  {
    float4 v;
    v.x = adjv[0] * 0.25f; v.y = adjv[1] * 0.25f;
    v.z = adjv[2] * 0.25f; v.w = adjv[3] * 0.25f;
    adjs4[t] = v;
  }
  __syncthreads();

  {
    const int dg = t & 31, jp = t >> 5;
    float4 f0 = {0,0,0,0}, f1 = {0,0,0,0}, f2 = {0,0,0,0}, f3 = {0,0,0,0};
    const float* xb = x + (size_t)(b * NN) * ND;
    for (int u = 0; u < 32; ++u) {
      const int j = jp * 32 + u;
      const float4 a = adjs4[j];
      const float4 xv = ld4(xb + (size_t)j * ND + dg * 4);
      f0.x = fmaf(a.x, xv.x, f0.x); f0.y = fmaf(a.x, xv.y, f0.y);
      f0.z = fmaf(a.x, xv.z, f0.z); f0.w = fmaf(a.x, xv.w, f0.w);
      f1.x = fmaf(a.y, xv.x, f1.x); f1.y = fmaf(a.y, xv.y, f1.y);
      f1.z = fmaf(a.y, xv.z, f1.z); f1.w = fmaf(a.y, xv.w, f1.w);
      f2.x = fmaf(a.z, xv.x, f2.x); f2.y = fmaf(a.z, xv.y, f2.y);
      f2.z = fmaf(a.z, xv.z, f2.z); f2.w = fmaf(a.z, xv.w, f2.w);
      f3.x = fmaf(a.w, xv.x, f3.x); f3.y = fmaf(a.w, xv.y, f3.y);
      f3.z = fmaf(a.w, xv.z, f3.z); f3.w = fmaf(a.w, xv.w, f3.w);
    }
    float4* pc4 = reinterpret_cast<float4*>(pcbuf);
    pc4[jp * 128 + 0 * 32 + dg] = f0;
    pc4[jp * 128 + 1 * 32 + dg] = f1;
    pc4[jp * 128 + 2 * 32 + dg] = f2;
    pc4[jp * 128 + 3 * 32 + dg] = f3;
  }
  __syncthreads();
  {
    float v = 0.f;
#pragma unroll
    for (int jp = 0; jp < 16; ++jp) v += pcbuf[jp * 512 + t];
    hsT[t] = v;
  }
  __syncthreads();
  {
    const int d = t & 127, eh = t >> 7;
    float a0 = 0.f, a1 = 0.f, a2 = 0.f, a3 = 0.f;
    for (int ee = 0; ee < 32; ++ee) {
      const int e = eh * 32 + ee;
      const float w = Wp[(size_t)e * ND + d];
      a0 = fmaf(hsT[0 * 128 + e], w, a0);
      a1 = fmaf(hsT[1 * 128 + e], w, a1);
      a2 = fmaf(hsT[2 * 128 + e], w, a2);
      a3 = fmaf(hsT[3 * 128 + e], w, a3);
    }
    float* pd = pcbuf;
    pd[eh * 512 + 0 * 128 + d] = a0;
    pd[eh * 512 + 1 * 128 + d] = a1;
    pd[eh * 512 + 2 * 128 + d] = a2;
    pd[eh * 512 + 3 * 128 + d] = a3;
  }
  __syncthreads();
  {
    const int d = t & 127;
    const float v = pcbuf[0 * 512 + t] + pcbuf[1 * 512 + t] +
                    pcbuf[2 * 512 + t] + pcbuf[3 * 512 + t] + bp[d];
    const int r = t >> 7;
    out[(size_t)(b * NN + i0 + r) * ND + d] = v;
  }
}

extern "C" void kernel_launch(void* const* d_in, const int* in_sizes, int n_in,
                              void* d_out, int out_size, void* d_ws, size_t ws_size,
                              hipStream_t stream) {
  const float* x  = (const float*)d_in[0];
  const float* W1 = (const float*)d_in[1];
  const float* b1 = (const float*)d_in[2];
  const float* W2 = (const float*)d_in[3];
  const float* b2 = (const float*)d_in[4];
  const float* Wp = (const float*)d_in[5];
  const float* bp = (const float*)d_in[6];
  float* out = (float*)d_out;

  const size_t nProj = (size_t)NB * NN * NH * NK;   // 262144
  const size_t nX2   = (size_t)NB * NN;             // 2048
  const size_t nDist = (size_t)NB * NN * NN;        // 1048576

  float* aj2 = (float*)d_ws;
  float* ai2 = aj2 + nProj;
  float* x2n = ai2 + nProj;
  float* dnt = x2n + nX2;           // 4 floats (1 used)
  float* dst = dnt + 4;

  dgf_proj<<<NB * NN / 8, 256, 0, stream>>>(x, W1, b1, W2, b2, ai2, aj2, x2n,
                                            dnt);

  if (ws_size >= (2 * nProj + nX2 + 4 + nDist) * sizeof(float)) {
    dgf_dist<<<NB * (NN / 8) * 2, 256, 0, stream>>>(x, x2n, dst);
    dgf_adj<<<NB * (NN / 4), 512, 0, stream>>>(x, W2, b2, Wp, bp, ai2, aj2,
                                               dst, out);
  } else {
    dgf_fused<<<NB * (NN / 4), 512, 0, stream>>>(x, W2, b2, Wp, bp, ai2, aj2,
                                                 x2n, out);
  }
}